// Round 10
// baseline (277.038 us; speedup 1.0000x reference)
//
#include <hip/hip_runtime.h>

typedef __bf16 bf16;
typedef bf16 bf16x8 __attribute__((ext_vector_type(8)));
typedef float f32x4 __attribute__((ext_vector_type(4)));
typedef float f32x16 __attribute__((ext_vector_type(16)));
typedef int i32x2 __attribute__((ext_vector_type(2)));

#define B_   4
#define N_   2048
#define DIM_ 1024
#define H_   16
#define DH_  64
#define M_   (B_ * N_)   // 8192

// log2(e) * (1/sqrt(64))
#define CEXP 0.18033688f

#define GLOBAL_CP(g) (const __attribute__((address_space(1))) void*)(g)
#define LDS_CP(l)    (__attribute__((address_space(3))) void*)(l)

// ---------------------------------------------------------------------------
// fused fp32 -> bf16 conversion for x | wqkv | wproj (contiguous dest in ws).
// ---------------------------------------------------------------------------
__global__ __launch_bounds__(256) void cvt_all(
    const float* __restrict__ x, const float* __restrict__ wq,
    const float* __restrict__ wp, bf16* __restrict__ o,
    int nx4, int nwq4, int nwp4)
{
    const int i = blockIdx.x * blockDim.x + threadIdx.x;
    const float* src; int si;
    if (i < nx4)                { src = x;  si = i; }
    else if (i < nx4 + nwq4)    { src = wq; si = i - nx4; }
    else                        { src = wp; si = i - nx4 - nwq4; }
    const float4 v = ((const float4*)src)[si];
    union { bf16 h[4]; uint2 u; } r;
    r.h[0] = (bf16)v.x; r.h[1] = (bf16)v.y;
    r.h[2] = (bf16)v.z; r.h[3] = (bf16)v.w;
    ((uint2*)o)[i] = r.u;
}

// ---------------------------------------------------------------------------
// GEMM (unchanged from R8): BK=64, DMA staging, XOR source-swizzled chunks.
// mode 0: fp32 C row-major.
// mode 1: scatter q/k [bh][n][d] (Q pre-scaled); V blocks (blockIdx.x>=16)
//   transpose their 128x128 C-tile through LDS so [bh][d][n] stores are
//   256B-contiguous runs (write amplification eliminated).
// ---------------------------------------------------------------------------
__global__ __launch_bounds__(256) void gemm_bt(
    const bf16* __restrict__ A, const bf16* __restrict__ Bm,
    int Ndim, int K, int mode,
    float* __restrict__ outf,
    bf16* __restrict__ qb, bf16* __restrict__ kbv, bf16* __restrict__ vbT)
{
    __shared__ bf16 smem[128 * 128];   // 32768 B: As | Bs, reused for V bounce
    bf16* As = smem;
    bf16* Bs = smem + 128 * 64;

    const int tid  = threadIdx.x;
    const int wave = tid >> 6;
    const int lane = tid & 63;
    const int quad = lane >> 4;
    const int lr   = lane & 15;
    const int wr   = wave >> 1, wc = wave & 1;
    const int m0 = blockIdx.y * 128;
    const int n0 = blockIdx.x * 128;

    f32x4 acc[4][4];
#pragma unroll
    for (int i = 0; i < 4; i++)
#pragma unroll
        for (int j = 0; j < 4; j++) acc[i][j] = f32x4{0.f, 0.f, 0.f, 0.f};

    const int sl8 = lane >> 3;
    const int sc8 = ((lane & 7) ^ (sl8 & 7)) * 8;

    for (int k0 = 0; k0 < K; k0 += 64) {
        __syncthreads();  // prev-iter frag reads done
#pragma unroll
        for (int c = 0; c < 4; c++) {
            const int ii  = wave * 4 + c;
            const int row = ii * 8 + sl8;
            __builtin_amdgcn_global_load_lds(
                GLOBAL_CP(A + (size_t)(m0 + row) * K + k0 + sc8),
                LDS_CP(&As[ii * 512 + lane * 8]), 16, 0, 0);
            __builtin_amdgcn_global_load_lds(
                GLOBAL_CP(Bm + (size_t)(n0 + row) * K + k0 + sc8),
                LDS_CP(&Bs[ii * 512 + lane * 8]), 16, 0, 0);
        }
        __syncthreads();  // staging visible (vmcnt drain)

#pragma unroll
        for (int s = 0; s < 2; s++) {
            bf16x8 af[4], bfr[4];
#pragma unroll
            for (int i = 0; i < 4; i++) {
                const int R = wr * 64 + i * 16 + lr;
                af[i] = *(const bf16x8*)(&As[R * 64 + (((s * 4 + quad) ^ (R & 7)) << 3)]);
            }
#pragma unroll
            for (int j = 0; j < 4; j++) {
                const int R = wc * 64 + j * 16 + lr;
                bfr[j] = *(const bf16x8*)(&Bs[R * 64 + (((s * 4 + quad) ^ (R & 7)) << 3)]);
            }
#pragma unroll
            for (int i = 0; i < 4; i++)
#pragma unroll
                for (int j = 0; j < 4; j++)
                    acc[i][j] = __builtin_amdgcn_mfma_f32_16x16x32_bf16(
                        af[i], bfr[j], acc[i][j], 0, 0, 0);
        }
    }

    if (mode == 1 && blockIdx.x >= 16) {
        // ---- V path: LDS-bounce transpose, coalesced [bh][d][n] stores ----
        __syncthreads();               // all As/Bs frag readers done
        const int b    = m0 >> 11;
        const int t0_0 = m0 & 2047;
        const int h0   = (n0 - 2048) >> 6;
#pragma unroll
        for (int i = 0; i < 4; i++) {
            const int c8 = wr * 16 + i * 4 + quad;
#pragma unroll
            for (int j = 0; j < 4; j++) {
                const int dl = wc * 64 + j * 16 + lr;
                const int p8 = c8 ^ (lr << 1);
                union { uint2 u; bf16 hh[4]; } p;
#pragma unroll
                for (int r = 0; r < 4; r++) p.hh[r] = (bf16)acc[i][j][r];
                *(uint2*)((char*)smem + dl * 256 + p8 * 8) = p.u;
            }
        }
        __syncthreads();
#pragma unroll
        for (int k = 0; k < 8; k++) {
            const int cid = k * 256 + tid;
            const int row = cid >> 4;          // d_local 0..127
            const int c16 = cid & 15;          // logical 16B chunk (t0)
            const uint4 v = *(const uint4*)((const char*)smem
                                + row * 256 + ((c16 ^ (row & 15)) * 16));
            bf16* dst = vbT + ((size_t)(b * 16 + h0 + (row >> 6)) * 64
                               + (row & 63)) * 2048 + t0_0 + c16 * 8;
            *(uint4*)dst = v;
        }
        return;
    }

#pragma unroll
    for (int i = 0; i < 4; i++) {
        const int mbase = m0 + wr * 64 + i * 16 + quad * 4;
#pragma unroll
        for (int j = 0; j < 4; j++) {
            const int n = n0 + wc * 64 + j * 16 + lr;
            if (mode == 0) {
#pragma unroll
                for (int r = 0; r < 4; r++)
                    outf[(size_t)(mbase + r) * Ndim + n] = acc[i][j][r];
            } else {
                const int h = (n >> 6) & 15;
                const int d = n & 63;
                const int b  = mbase >> 11;
                const int t0 = mbase & 2047;
                bf16* dst = (n < 1024) ? qb : kbv;
                const float sc = (n < 1024) ? CEXP : 1.0f;
#pragma unroll
                for (int r = 0; r < 4; r++)
                    dst[(((size_t)(b * 16 + h)) * 2048 + t0 + r) * 64 + d] =
                        (bf16)(acc[i][j][r] * sc);
            }
        }
    }
}

// ---------------------------------------------------------------------------
// Flash attention v19 = v18's ones-MFMA row-sum fitted INSIDE the 128-reg /
// 4-blocks-per-CU envelope (v18's mechanism worked — VALUBusy 55->43 — but
// its +36 regs crossed 128 and cost a resident block, R9: occupancy 32->23).
// Register trims vs v18:
//  - kZ dropped (-16): explicit e zero-init (v17's form).
//  - kofs 8->4 (-4): kofs[kbk=1] == kofs[kbk=0] + 4096 exactly (rr&15, pc
//    invariant under kbk) -> compile-time +4096 folds into ds_read offset.
//  - vofs 8->4 (-4): vofs[kbk=1] == vofs[kbk=0] ^ 64 (chv bit2 -> pv^4);
//    kbk*64 is a compile-time constant in the unrolled loop.
//  - ssum/lrow/bpermute/epilogue-shuffles gone (sacc lane-local).
// Net vs v17: ~+10 regs. Tripwires: OccupancyPercent ~32 (23 = overflow,
// revert); WRITE_SIZE == 16384 (spill).
// ---------------------------------------------------------------------------
__global__ __launch_bounds__(256, 3) void attn_kernel(
    const bf16* __restrict__ qb, const bf16* __restrict__ kb,
    const bf16* __restrict__ vbT, bf16* __restrict__ ao)
{
    __shared__ bf16 Ks[2][32 * 128];   // 8KB per buffer, paired-key rows
    __shared__ bf16 Vs[2][32 * 128];   // 8KB per buffer, paired-d rows

    const int tid  = threadIdx.x;
    const int wave = tid >> 6;
    const int lane = tid & 63;
    const int l31  = lane & 31;
    const int hh   = lane >> 5;       // half-wave index

    // XCD swizzle: one head's 16 q-tiles on one XCD
    const int bid = blockIdx.x;
    const int qt  = (bid >> 3) & 15;
    const int bh  = ((bid >> 7) << 3) | (bid & 7);

    const bf16* Q  = qb  + (size_t)bh * N_ * DH_;
    const bf16* Kp = kb  + (size_t)bh * N_ * DH_;
    const bf16* Vp = vbT + (size_t)bh * DH_ * N_;   // [d][n]

    // Q B-frags: B[q=l31][d = ks*16 + hh*8 + j], loaded once from global
    bf16x8 qf[4];
#pragma unroll
    for (int ks = 0; ks < 4; ks++)
        qf[ks] = *(const bf16x8*)(Q + (size_t)(qt * 128 + wave * 32 + l31) * DH_
                                    + ks * 16 + hh * 8);

    bf16x8 onesb;
#pragma unroll
    for (int j = 0; j < 8; j++) onesb[j] = (bf16)1.0f;

    // ---- hoisted LDS read byte-offsets, kbk=0 only (kbk=1 derived:
    //      kofs +4096 immediate, vofs ^64 compile-time const) ----
    int kofs[4];   // [ks]
#pragma unroll
    for (int ks = 0; ks < 4; ks++) {
        const int R  = l31;                 // kbk = 0
        const int rr = R >> 1;
        const int ch = ks * 2 + hh;
        const int pc = (((R & 1) << 3) | ch) ^ (rr & 15);
        kofs[ks] = rr * 256 + pc * 16;
    }
    int vofs[4];   // [dblk*2 + half]
#pragma unroll
    for (int dblk = 0; dblk < 2; dblk++)
#pragma unroll
        for (int half = 0; half < 2; half++) {
            const int Rv  = dblk * 32 + l31;
            const int rv  = Rv >> 1;
            const int chv = half * 2 + hh;  // kbk = 0
            const int pv_ = (((Rv & 1) << 3) | chv) ^ (rv & 15);
            vofs[dblk * 2 + half] = rv * 256 + pv_ * 16;
        }

    // ---- hoisted staging addresses ----
    const int sr = lane >> 4;
    const int sp = lane & 15;
    const bf16* ksrc[2];
    const bf16* vsrc[2];
    int sdst[2];
#pragma unroll
    for (int c2 = 0; c2 < 2; c2++) {
        const int ii  = wave * 2 + c2;
        const int rr2 = ii * 4 + sr;
        const int lc  = sp ^ (rr2 & 15);
        const int kk  = 2 * rr2 + (lc >> 3);
        const int d0  = (lc & 7) * 8;
        ksrc[c2] = Kp + (size_t)kk * DH_ + d0;   // t=0
        vsrc[c2] = Vp + (size_t)kk * N_ + d0;    // t=0
        sdst[c2] = ii * 1024 + lane * 16;        // bytes, buf0
    }

    const char* ksB = (const char*)Ks;
    const char* vsB = (const char*)Vs;
    char* ksBm = (char*)Ks;
    char* vsBm = (char*)Vs;

    f32x16 oacc[2];
    f32x16 sacc;
#pragma unroll
    for (int r = 0; r < 16; r++) { oacc[0][r] = 0.f; oacc[1][r] = 0.f; sacc[r] = 0.f; }

#define STAGE()                                                               \
    {                                                                         \
        _Pragma("unroll")                                                     \
        for (int c2 = 0; c2 < 2; c2++) {                                      \
            __builtin_amdgcn_global_load_lds(GLOBAL_CP(ksrc[c2]),             \
                LDS_CP(ksBm + sdst[c2]), 16, 0, 0);                           \
            __builtin_amdgcn_global_load_lds(GLOBAL_CP(vsrc[c2]),             \
                LDS_CP(vsBm + sdst[c2]), 16, 0, 0);                           \
            ksrc[c2] += 64 * DH_;   /* +8192 B: next key-tile */              \
            vsrc[c2] += 64;         /* +128 B: next key-column */             \
            sdst[c2] ^= 8192;       /* alternate buffer */                    \
        }                                                                     \
    }

#define TILE(BUFB)                                                            \
    {                                                                         \
        _Pragma("unroll")                                                     \
        for (int kbk = 0; kbk < 2; kbk++) {                                   \
            f32x16 e;                                                         \
            _Pragma("unroll")                                                 \
            for (int r = 0; r < 16; r++) e[r] = 0.f;                          \
            __builtin_amdgcn_s_setprio(1);                                    \
            _Pragma("unroll")                                                 \
            for (int ks = 0; ks < 4; ks++) {                                  \
                bf16x8 ak = *(const bf16x8*)(ksB + kofs[ks]                   \
                                             + kbk * 4096 + (BUFB));          \
                e = __builtin_amdgcn_mfma_f32_32x32x16_bf16(                  \
                        ak, qf[ks], e, 0, 0, 0);                              \
            }                                                                 \
            __builtin_amdgcn_s_setprio(0);                                    \
            bf16x8 bv[2][2];                                                  \
            _Pragma("unroll")                                                 \
            for (int dblk = 0; dblk < 2; dblk++)                              \
                _Pragma("unroll")                                             \
                for (int half = 0; half < 2; half++)                          \
                    bv[dblk][half] = *(const bf16x8*)(vsB                     \
                        + (vofs[dblk * 2 + half] ^ (kbk * 64)) + (BUFB));     \
            _Pragma("unroll")                                                 \
            for (int r = 0; r < 16; r++) e[r] = __builtin_amdgcn_exp2f(e[r]); \
            uint g[8];                                                        \
            _Pragma("unroll")                                                 \
            for (int m = 0; m < 8; m++) {                                     \
                union { uint u; bf16 h2[2]; } pk;                             \
                pk.h2[0] = (bf16)e[2 * m];                                    \
                pk.h2[1] = (bf16)e[2 * m + 1];                                \
                g[m] = pk.u;                                                  \
            }                                                                 \
            const i32x2 s0 = __builtin_amdgcn_permlane32_swap((int)g[0], (int)g[2], false, false); \
            const i32x2 s1 = __builtin_amdgcn_permlane32_swap((int)g[1], (int)g[3], false, false); \
            const i32x2 s2 = __builtin_amdgcn_permlane32_swap((int)g[4], (int)g[6], false, false); \
            const i32x2 s3 = __builtin_amdgcn_permlane32_swap((int)g[5], (int)g[7], false, false); \
            union { uint u[4]; bf16x8 v; } p0u, p1u;                          \
            p0u.u[0] = (uint)s0[0]; p0u.u[1] = (uint)s1[0];                   \
            p0u.u[2] = (uint)s0[1]; p0u.u[3] = (uint)s1[1];                   \
            p1u.u[0] = (uint)s2[0]; p1u.u[1] = (uint)s3[0];                   \
            p1u.u[2] = (uint)s2[1]; p1u.u[3] = (uint)s3[1];                   \
            __builtin_amdgcn_s_setprio(1);                                    \
            sacc = __builtin_amdgcn_mfma_f32_32x32x16_bf16(                   \
                p0u.v, onesb, sacc, 0, 0, 0);                                 \
            sacc = __builtin_amdgcn_mfma_f32_32x32x16_bf16(                   \
                p1u.v, onesb, sacc, 0, 0, 0);                                 \
            _Pragma("unroll")                                                 \
            for (int dblk = 0; dblk < 2; dblk++) {                            \
                oacc[dblk] = __builtin_amdgcn_mfma_f32_32x32x16_bf16(         \
                    p0u.v, bv[dblk][0], oacc[dblk], 0, 0, 0);                 \
                oacc[dblk] = __builtin_amdgcn_mfma_f32_32x32x16_bf16(         \
                    p1u.v, bv[dblk][1], oacc[dblk], 0, 0, 0);                 \
            }                                                                 \
            __builtin_amdgcn_s_setprio(0);                                    \
        }                                                                     \
    }

    STAGE();             // t=0 -> buf0; srcs advance to t=1, dst -> buf1
    __syncthreads();     // tile 0 visible

    for (int tt = 0; tt < 16; tt++) {
        STAGE();         // t=2tt+1 -> buf1
        TILE(0);         // compute tile 2tt from buf0
        __syncthreads(); // buf1 staged; buf0 readers done
        if (tt < 15) STAGE();   // t=2tt+2 -> buf0
        TILE(8192);      // compute tile 2tt+1 from buf1
        __syncthreads(); // buf0 staged; buf1 readers done
    }
#undef STAGE
#undef TILE

    // epilogue: O row q=(r&3)+8*(r>>2)+4*hh, col d=dblk*32+l31.
    // sacc[r] holds the full row sum for the SAME q-row in every lane.
    const int head = bh & 15;
    const int b    = bh >> 4;
#pragma unroll
    for (int r = 0; r < 16; r++) {
        const int qr  = (r & 3) + 8 * (r >> 2) + 4 * hh;
        const float inv = 1.0f / sacc[r];
        const int qrow = qt * 128 + wave * 32 + qr;
#pragma unroll
        for (int dblk = 0; dblk < 2; dblk++)
            ao[((size_t)(b * 2048 + qrow)) * 1024 + head * 64 + dblk * 32 + l31] =
                (bf16)(oacc[dblk][r] * inv);
    }
}

// ---------------------------------------------------------------------------
extern "C" void kernel_launch(void* const* d_in, const int* in_sizes, int n_in,
                              void* d_out, int out_size, void* d_ws, size_t ws_size,
                              hipStream_t stream)
{
    const float* x     = (const float*)d_in[0];   // [8192 x 1024] fp32
    const float* wqkv  = (const float*)d_in[1];   // [3072 x 1024] fp32
    const float* wproj = (const float*)d_in[2];   // [1024 x 1024] fp32
    float* out = (float*)d_out;                   // [8192 x 1024] fp32

    const size_t nx  = (size_t)M_ * DIM_;
    const size_t nwq = (size_t)3 * DIM_ * DIM_;
    const size_t nwp = (size_t)DIM_ * DIM_;
    const size_t seg = (size_t)B_ * H_ * N_ * DH_;

    bf16* xb     = (bf16*)d_ws;        // dead after QKV gemm; ao overlays it
    bf16* wqkvb  = xb + nx;            // contiguous with xb (cvt_all dest)
    bf16* wprojb = wqkvb + nwq;
    bf16* qb     = wprojb + nwp;
    bf16* kb     = qb + seg;
    bf16* vbT    = kb + seg;           // [bh][d][n]
    bf16* ao     = xb;

    const int nx4  = (int)(nx / 4), nwq4 = (int)(nwq / 4), nwp4 = (int)(nwp / 4);
    cvt_all<<<(nx4 + nwq4 + nwp4) / 256, 256, 0, stream>>>(
        x, wqkv, wproj, xb, nx4, nwq4, nwp4);

    gemm_bt<<<dim3(24, 64), 256, 0, stream>>>(xb, wqkvb, 3 * DIM_, DIM_, 1,
                                              nullptr, qb, kb, vbT);
    attn_kernel<<<dim3(1024), 256, 0, stream>>>(qb, kb, vbT, ao);
    gemm_bt<<<dim3(8, 64), 256, 0, stream>>>(ao, wprojb, DIM_, DIM_, 0,
                                             out, nullptr, nullptr, nullptr);
}

// Round 11
// 275.105 us; speedup vs baseline: 1.0070x; 1.0070x over previous
//
#include <hip/hip_runtime.h>

typedef __bf16 bf16;
typedef bf16 bf16x8 __attribute__((ext_vector_type(8)));
typedef float f32x4 __attribute__((ext_vector_type(4)));
typedef float f32x16 __attribute__((ext_vector_type(16)));
typedef int i32x2 __attribute__((ext_vector_type(2)));

#define B_   4
#define N_   2048
#define DIM_ 1024
#define H_   16
#define DH_  64
#define M_   (B_ * N_)   // 8192

// log2(e) * (1/sqrt(64))
#define CEXP 0.18033688f

#define GLOBAL_CP(g) (const __attribute__((address_space(1))) void*)(g)
#define LDS_CP(l)    (__attribute__((address_space(3))) void*)(l)

// ---------------------------------------------------------------------------
// fused fp32 -> bf16 conversion for x | wqkv | wproj (contiguous dest in ws).
// v2: 2 float4 quads per thread (6144 blocks, was 12288). Segment boundaries
// (nx4, nx4+nwq4) are even, thread quads are (2i, 2i+1) -> never straddle.
// ---------------------------------------------------------------------------
__global__ __launch_bounds__(256) void cvt_all(
    const float* __restrict__ x, const float* __restrict__ wq,
    const float* __restrict__ wp, bf16* __restrict__ o,
    int nx4, int nwq4, int nwp4)
{
    const int i0 = (blockIdx.x * blockDim.x + threadIdx.x) * 2;
#pragma unroll
    for (int u = 0; u < 2; u++) {
        const int i = i0 + u;
        const float* src; int si;
        if (i < nx4)                { src = x;  si = i; }
        else if (i < nx4 + nwq4)    { src = wq; si = i - nx4; }
        else                        { src = wp; si = i - nx4 - nwq4; }
        const float4 v = ((const float4*)src)[si];
        union { bf16 h[4]; uint2 u2; } r;
        r.h[0] = (bf16)v.x; r.h[1] = (bf16)v.y;
        r.h[2] = (bf16)v.z; r.h[3] = (bf16)v.w;
        ((uint2*)o)[i] = r.u2;
    }
}

// ---------------------------------------------------------------------------
// GEMM (unchanged from R8): BK=64, DMA staging, XOR source-swizzled chunks.
// mode 0: fp32 C row-major.
// mode 1: scatter q/k [bh][n][d] (Q pre-scaled); V blocks (blockIdx.x>=16)
//   transpose their 128x128 C-tile through LDS so [bh][d][n] stores are
//   256B-contiguous runs (write amplification eliminated).
// ---------------------------------------------------------------------------
__global__ __launch_bounds__(256) void gemm_bt(
    const bf16* __restrict__ A, const bf16* __restrict__ Bm,
    int Ndim, int K, int mode,
    float* __restrict__ outf,
    bf16* __restrict__ qb, bf16* __restrict__ kbv, bf16* __restrict__ vbT)
{
    __shared__ bf16 smem[128 * 128];   // 32768 B: As | Bs, reused for V bounce
    bf16* As = smem;
    bf16* Bs = smem + 128 * 64;

    const int tid  = threadIdx.x;
    const int wave = tid >> 6;
    const int lane = tid & 63;
    const int quad = lane >> 4;
    const int lr   = lane & 15;
    const int wr   = wave >> 1, wc = wave & 1;
    const int m0 = blockIdx.y * 128;
    const int n0 = blockIdx.x * 128;

    f32x4 acc[4][4];
#pragma unroll
    for (int i = 0; i < 4; i++)
#pragma unroll
        for (int j = 0; j < 4; j++) acc[i][j] = f32x4{0.f, 0.f, 0.f, 0.f};

    const int sl8 = lane >> 3;
    const int sc8 = ((lane & 7) ^ (sl8 & 7)) * 8;

    for (int k0 = 0; k0 < K; k0 += 64) {
        __syncthreads();  // prev-iter frag reads done
#pragma unroll
        for (int c = 0; c < 4; c++) {
            const int ii  = wave * 4 + c;
            const int row = ii * 8 + sl8;
            __builtin_amdgcn_global_load_lds(
                GLOBAL_CP(A + (size_t)(m0 + row) * K + k0 + sc8),
                LDS_CP(&As[ii * 512 + lane * 8]), 16, 0, 0);
            __builtin_amdgcn_global_load_lds(
                GLOBAL_CP(Bm + (size_t)(n0 + row) * K + k0 + sc8),
                LDS_CP(&Bs[ii * 512 + lane * 8]), 16, 0, 0);
        }
        __syncthreads();  // staging visible (vmcnt drain)

#pragma unroll
        for (int s = 0; s < 2; s++) {
            bf16x8 af[4], bfr[4];
#pragma unroll
            for (int i = 0; i < 4; i++) {
                const int R = wr * 64 + i * 16 + lr;
                af[i] = *(const bf16x8*)(&As[R * 64 + (((s * 4 + quad) ^ (R & 7)) << 3)]);
            }
#pragma unroll
            for (int j = 0; j < 4; j++) {
                const int R = wc * 64 + j * 16 + lr;
                bfr[j] = *(const bf16x8*)(&Bs[R * 64 + (((s * 4 + quad) ^ (R & 7)) << 3)]);
            }
#pragma unroll
            for (int i = 0; i < 4; i++)
#pragma unroll
                for (int j = 0; j < 4; j++)
                    acc[i][j] = __builtin_amdgcn_mfma_f32_16x16x32_bf16(
                        af[i], bfr[j], acc[i][j], 0, 0, 0);
        }
    }

    if (mode == 1 && blockIdx.x >= 16) {
        // ---- V path: LDS-bounce transpose, coalesced [bh][d][n] stores ----
        __syncthreads();               // all As/Bs frag readers done
        const int b    = m0 >> 11;
        const int t0_0 = m0 & 2047;
        const int h0   = (n0 - 2048) >> 6;
#pragma unroll
        for (int i = 0; i < 4; i++) {
            const int c8 = wr * 16 + i * 4 + quad;
#pragma unroll
            for (int j = 0; j < 4; j++) {
                const int dl = wc * 64 + j * 16 + lr;
                const int p8 = c8 ^ (lr << 1);
                union { uint2 u; bf16 hh[4]; } p;
#pragma unroll
                for (int r = 0; r < 4; r++) p.hh[r] = (bf16)acc[i][j][r];
                *(uint2*)((char*)smem + dl * 256 + p8 * 8) = p.u;
            }
        }
        __syncthreads();
#pragma unroll
        for (int k = 0; k < 8; k++) {
            const int cid = k * 256 + tid;
            const int row = cid >> 4;          // d_local 0..127
            const int c16 = cid & 15;          // logical 16B chunk (t0)
            const uint4 v = *(const uint4*)((const char*)smem
                                + row * 256 + ((c16 ^ (row & 15)) * 16));
            bf16* dst = vbT + ((size_t)(b * 16 + h0 + (row >> 6)) * 64
                               + (row & 63)) * 2048 + t0_0 + c16 * 8;
            *(uint4*)dst = v;
        }
        return;
    }

#pragma unroll
    for (int i = 0; i < 4; i++) {
        const int mbase = m0 + wr * 64 + i * 16 + quad * 4;
#pragma unroll
        for (int j = 0; j < 4; j++) {
            const int n = n0 + wc * 64 + j * 16 + lr;
            if (mode == 0) {
#pragma unroll
                for (int r = 0; r < 4; r++)
                    outf[(size_t)(mbase + r) * Ndim + n] = acc[i][j][r];
            } else {
                const int h = (n >> 6) & 15;
                const int d = n & 63;
                const int b  = mbase >> 11;
                const int t0 = mbase & 2047;
                bf16* dst = (n < 1024) ? qb : kbv;
                const float sc = (n < 1024) ? CEXP : 1.0f;
#pragma unroll
                for (int r = 0; r < 4; r++)
                    dst[(((size_t)(b * 16 + h)) * 2048 + t0 + r) * 64 + d] =
                        (bf16)(acc[i][j][r] * sc);
            }
        }
    }
}

// ---------------------------------------------------------------------------
// Flash attention v17 — R8-exact revert (best measured: attn 88.6µs, total
// 273.79µs). R9/R10 established that the ones-MFMA row-sum variants cannot
// fit the 4-blocks/CU register envelope (AGPR growth, occupancy 32->23.6,
// net -9µs both times). This is the 2-barrier structure's fitted optimum:
//  - hoisted kofs/vofs LDS byte-offsets at the (256,3) register budget
//    (in-register, no spill: WRITE_SIZE==16384 tripwire)
//  - buf0/buf1 unrolled tile pairs (buffer byte = compile-time immediate)
//  - VALU row-sum + shfl epilogue, raw v_exp_f32, permlane32_swap exchange,
//    0-conflict paired-row K/V layout, double-buffered DMA staging, setprio.
// ---------------------------------------------------------------------------
__global__ __launch_bounds__(256, 3) void attn_kernel(
    const bf16* __restrict__ qb, const bf16* __restrict__ kb,
    const bf16* __restrict__ vbT, bf16* __restrict__ ao)
{
    __shared__ bf16 Ks[2][32 * 128];   // 8KB per buffer, paired-key rows
    __shared__ bf16 Vs[2][32 * 128];   // 8KB per buffer, paired-d rows

    const int tid  = threadIdx.x;
    const int wave = tid >> 6;
    const int lane = tid & 63;
    const int l31  = lane & 31;
    const int hh   = lane >> 5;       // half-wave index

    // XCD swizzle: one head's 16 q-tiles on one XCD
    const int bid = blockIdx.x;
    const int qt  = (bid >> 3) & 15;
    const int bh  = ((bid >> 7) << 3) | (bid & 7);

    const bf16* Q  = qb  + (size_t)bh * N_ * DH_;
    const bf16* Kp = kb  + (size_t)bh * N_ * DH_;
    const bf16* Vp = vbT + (size_t)bh * DH_ * N_;   // [d][n]

    // Q B-frags: B[q=l31][d = ks*16 + hh*8 + j], loaded once from global
    bf16x8 qf[4];
#pragma unroll
    for (int ks = 0; ks < 4; ks++)
        qf[ks] = *(const bf16x8*)(Q + (size_t)(qt * 128 + wave * 32 + l31) * DH_
                                    + ks * 16 + hh * 8);

    // ---- hoisted LDS read byte-offsets (t-invariant) ----
    int kofs[8];   // [kbk*4 + ks]
#pragma unroll
    for (int kbk = 0; kbk < 2; kbk++)
#pragma unroll
        for (int ks = 0; ks < 4; ks++) {
            const int R  = kbk * 32 + l31;
            const int rr = R >> 1;
            const int ch = ks * 2 + hh;
            const int pc = (((R & 1) << 3) | ch) ^ (rr & 15);
            kofs[kbk * 4 + ks] = rr * 256 + pc * 16;
        }
    int vofs[8];   // [kbk*4 + dblk*2 + half]
#pragma unroll
    for (int kbk = 0; kbk < 2; kbk++)
#pragma unroll
        for (int dblk = 0; dblk < 2; dblk++)
#pragma unroll
            for (int half = 0; half < 2; half++) {
                const int Rv  = dblk * 32 + l31;
                const int rv  = Rv >> 1;
                const int chv = kbk * 4 + half * 2 + hh;
                const int pv_ = (((Rv & 1) << 3) | chv) ^ (rv & 15);
                vofs[kbk * 4 + dblk * 2 + half] = rv * 256 + pv_ * 16;
            }

    // ---- hoisted staging addresses ----
    const int sr = lane >> 4;
    const int sp = lane & 15;
    const bf16* ksrc[2];
    const bf16* vsrc[2];
    int sdst[2];
#pragma unroll
    for (int c2 = 0; c2 < 2; c2++) {
        const int ii  = wave * 2 + c2;
        const int rr2 = ii * 4 + sr;
        const int lc  = sp ^ (rr2 & 15);
        const int kk  = 2 * rr2 + (lc >> 3);
        const int d0  = (lc & 7) * 8;
        ksrc[c2] = Kp + (size_t)kk * DH_ + d0;   // t=0
        vsrc[c2] = Vp + (size_t)kk * N_ + d0;    // t=0
        sdst[c2] = ii * 1024 + lane * 16;        // bytes, buf0
    }

    const char* ksB = (const char*)Ks;
    const char* vsB = (const char*)Vs;
    char* ksBm = (char*)Ks;
    char* vsBm = (char*)Vs;

    f32x16 oacc[2];
#pragma unroll
    for (int r = 0; r < 16; r++) { oacc[0][r] = 0.f; oacc[1][r] = 0.f; }
    float lrow = 0.f;

#define STAGE()                                                               \
    {                                                                         \
        _Pragma("unroll")                                                     \
        for (int c2 = 0; c2 < 2; c2++) {                                      \
            __builtin_amdgcn_global_load_lds(GLOBAL_CP(ksrc[c2]),             \
                LDS_CP(ksBm + sdst[c2]), 16, 0, 0);                           \
            __builtin_amdgcn_global_load_lds(GLOBAL_CP(vsrc[c2]),             \
                LDS_CP(vsBm + sdst[c2]), 16, 0, 0);                           \
            ksrc[c2] += 64 * DH_;   /* +8192 B: next key-tile */              \
            vsrc[c2] += 64;         /* +128 B: next key-column */             \
            sdst[c2] ^= 8192;       /* alternate buffer */                    \
        }                                                                     \
    }

#define TILE(BUFB)                                                            \
    {                                                                         \
        float ssum = 0.f;                                                     \
        _Pragma("unroll")                                                     \
        for (int kbk = 0; kbk < 2; kbk++) {                                   \
            f32x16 e;                                                         \
            _Pragma("unroll")                                                 \
            for (int r = 0; r < 16; r++) e[r] = 0.f;                          \
            __builtin_amdgcn_s_setprio(1);                                    \
            _Pragma("unroll")                                                 \
            for (int ks = 0; ks < 4; ks++) {                                  \
                bf16x8 ak = *(const bf16x8*)(ksB + kofs[kbk * 4 + ks] + (BUFB)); \
                e = __builtin_amdgcn_mfma_f32_32x32x16_bf16(                  \
                        ak, qf[ks], e, 0, 0, 0);                              \
            }                                                                 \
            __builtin_amdgcn_s_setprio(0);                                    \
            bf16x8 bv[2][2];                                                  \
            _Pragma("unroll")                                                 \
            for (int dblk = 0; dblk < 2; dblk++)                              \
                _Pragma("unroll")                                             \
                for (int half = 0; half < 2; half++)                          \
                    bv[dblk][half] = *(const bf16x8*)(                        \
                        vsB + vofs[kbk * 4 + dblk * 2 + half] + (BUFB));      \
            _Pragma("unroll")                                                 \
            for (int r = 0; r < 16; r++) e[r] = __builtin_amdgcn_exp2f(e[r]); \
            _Pragma("unroll")                                                 \
            for (int r = 0; r < 16; r++) ssum += e[r];                        \
            uint g[8];                                                        \
            _Pragma("unroll")                                                 \
            for (int m = 0; m < 8; m++) {                                     \
                union { uint u; bf16 h2[2]; } pk;                             \
                pk.h2[0] = (bf16)e[2 * m];                                    \
                pk.h2[1] = (bf16)e[2 * m + 1];                                \
                g[m] = pk.u;                                                  \
            }                                                                 \
            const i32x2 s0 = __builtin_amdgcn_permlane32_swap((int)g[0], (int)g[2], false, false); \
            const i32x2 s1 = __builtin_amdgcn_permlane32_swap((int)g[1], (int)g[3], false, false); \
            const i32x2 s2 = __builtin_amdgcn_permlane32_swap((int)g[4], (int)g[6], false, false); \
            const i32x2 s3 = __builtin_amdgcn_permlane32_swap((int)g[5], (int)g[7], false, false); \
            union { uint u[4]; bf16x8 v; } p0u, p1u;                          \
            p0u.u[0] = (uint)s0[0]; p0u.u[1] = (uint)s1[0];                   \
            p0u.u[2] = (uint)s0[1]; p0u.u[3] = (uint)s1[1];                   \
            p1u.u[0] = (uint)s2[0]; p1u.u[1] = (uint)s3[0];                   \
            p1u.u[2] = (uint)s2[1]; p1u.u[3] = (uint)s3[1];                   \
            __builtin_amdgcn_s_setprio(1);                                    \
            _Pragma("unroll")                                                 \
            for (int dblk = 0; dblk < 2; dblk++) {                            \
                oacc[dblk] = __builtin_amdgcn_mfma_f32_32x32x16_bf16(         \
                    p0u.v, bv[dblk][0], oacc[dblk], 0, 0, 0);                 \
                oacc[dblk] = __builtin_amdgcn_mfma_f32_32x32x16_bf16(         \
                    p1u.v, bv[dblk][1], oacc[dblk], 0, 0, 0);                 \
            }                                                                 \
            __builtin_amdgcn_s_setprio(0);                                    \
        }                                                                     \
        ssum += __shfl_xor(ssum, 32);                                         \
        lrow += ssum;                                                         \
    }

    STAGE();             // t=0 -> buf0; srcs advance to t=1, dst -> buf1
    __syncthreads();     // tile 0 visible

    for (int tt = 0; tt < 16; tt++) {
        STAGE();         // t=2tt+1 -> buf1
        TILE(0);         // compute tile 2tt from buf0
        __syncthreads(); // buf1 staged; buf0 readers done
        if (tt < 15) STAGE();   // t=2tt+2 -> buf0
        TILE(8192);      // compute tile 2tt+1 from buf1
        __syncthreads(); // buf0 staged; buf1 readers done
    }
#undef STAGE
#undef TILE

    // epilogue: O row q=(r&3)+8*(r>>2)+4*hh, col d=dblk*32+l31.
    const int head = bh & 15;
    const int b    = bh >> 4;
    const float linv = 1.0f / lrow;     // valid at lane with l31 == q
#pragma unroll
    for (int r = 0; r < 16; r++) {
        const int qr  = (r & 3) + 8 * (r >> 2) + 4 * hh;
        const float inv = __shfl(linv, qr);     // lane qr holds q=qr
        const int qrow = qt * 128 + wave * 32 + qr;
#pragma unroll
        for (int dblk = 0; dblk < 2; dblk++)
            ao[((size_t)(b * 2048 + qrow)) * 1024 + head * 64 + dblk * 32 + l31] =
                (bf16)(oacc[dblk][r] * inv);
    }
}

// ---------------------------------------------------------------------------
extern "C" void kernel_launch(void* const* d_in, const int* in_sizes, int n_in,
                              void* d_out, int out_size, void* d_ws, size_t ws_size,
                              hipStream_t stream)
{
    const float* x     = (const float*)d_in[0];   // [8192 x 1024] fp32
    const float* wqkv  = (const float*)d_in[1];   // [3072 x 1024] fp32
    const float* wproj = (const float*)d_in[2];   // [1024 x 1024] fp32
    float* out = (float*)d_out;                   // [8192 x 1024] fp32

    const size_t nx  = (size_t)M_ * DIM_;
    const size_t nwq = (size_t)3 * DIM_ * DIM_;
    const size_t nwp = (size_t)DIM_ * DIM_;
    const size_t seg = (size_t)B_ * H_ * N_ * DH_;

    bf16* xb     = (bf16*)d_ws;        // dead after QKV gemm; ao overlays it
    bf16* wqkvb  = xb + nx;            // contiguous with xb (cvt_all dest)
    bf16* wprojb = wqkvb + nwq;
    bf16* qb     = wprojb + nwp;
    bf16* kb     = qb + seg;
    bf16* vbT    = kb + seg;           // [bh][d][n]
    bf16* ao     = xb;

    const int nx4  = (int)(nx / 4), nwq4 = (int)(nwq / 4), nwp4 = (int)(nwp / 4);
    cvt_all<<<(nx4 + nwq4 + nwp4) / 512, 256, 0, stream>>>(
        x, wqkv, wproj, xb, nx4, nwq4, nwp4);

    gemm_bt<<<dim3(24, 64), 256, 0, stream>>>(xb, wqkvb, 3 * DIM_, DIM_, 1,
                                              nullptr, qb, kb, vbT);
    attn_kernel<<<dim3(1024), 256, 0, stream>>>(qb, kb, vbT, ao);
    gemm_bt<<<dim3(8, 64), 256, 0, stream>>>(ao, wprojb, DIM_, DIM_, 0,
                                             out, nullptr, nullptr, nullptr);
}

// Round 12
// 263.082 us; speedup vs baseline: 1.0530x; 1.0457x over previous
//
#include <hip/hip_runtime.h>

typedef __bf16 bf16;
typedef bf16 bf16x8 __attribute__((ext_vector_type(8)));
typedef float f32x4 __attribute__((ext_vector_type(4)));
typedef float f32x16 __attribute__((ext_vector_type(16)));
typedef int i32x2 __attribute__((ext_vector_type(2)));

#define B_   4
#define N_   2048
#define DIM_ 1024
#define H_   16
#define DH_  64
#define M_   (B_ * N_)   // 8192

// log2(e) * (1/sqrt(64))
#define CEXP 0.18033688f

#define GLOBAL_CP(g) (const __attribute__((address_space(1))) void*)(g)
#define LDS_CP(l)    (__attribute__((address_space(3))) void*)(l)

// ---------------------------------------------------------------------------
// fused fp32 -> bf16 conversion for x | wqkv | wproj (contiguous dest in ws).
// 2 float4 quads per thread; segment boundaries are even so pairs never
// straddle.
// ---------------------------------------------------------------------------
__global__ __launch_bounds__(256) void cvt_all(
    const float* __restrict__ x, const float* __restrict__ wq,
    const float* __restrict__ wp, bf16* __restrict__ o,
    int nx4, int nwq4, int nwp4)
{
    const int i0 = (blockIdx.x * blockDim.x + threadIdx.x) * 2;
#pragma unroll
    for (int u = 0; u < 2; u++) {
        const int i = i0 + u;
        const float* src; int si;
        if (i < nx4)                { src = x;  si = i; }
        else if (i < nx4 + nwq4)    { src = wq; si = i - nx4; }
        else                        { src = wp; si = i - nx4 - nwq4; }
        const float4 v = ((const float4*)src)[si];
        union { bf16 h[4]; uint2 u2; } r;
        r.h[0] = (bf16)v.x; r.h[1] = (bf16)v.y;
        r.h[2] = (bf16)v.z; r.h[3] = (bf16)v.w;
        ((uint2*)o)[i] = r.u2;
    }
}

// ---------------------------------------------------------------------------
// QKV GEMM (unchanged from R8/R11): BK=64, DMA staging, XOR source-swizzled
// chunks. mode 1: scatter q/k [bh][n][d] (Q pre-scaled); V blocks
// (blockIdx.x>=16) transpose their 128x128 C-tile through LDS so [bh][d][n]
// stores are 256B-contiguous runs.
// ---------------------------------------------------------------------------
__global__ __launch_bounds__(256) void gemm_bt(
    const bf16* __restrict__ A, const bf16* __restrict__ Bm,
    int Ndim, int K, int mode,
    float* __restrict__ outf,
    bf16* __restrict__ qb, bf16* __restrict__ kbv, bf16* __restrict__ vbT)
{
    __shared__ bf16 smem[128 * 128];   // 32768 B: As | Bs, reused for V bounce
    bf16* As = smem;
    bf16* Bs = smem + 128 * 64;

    const int tid  = threadIdx.x;
    const int wave = tid >> 6;
    const int lane = tid & 63;
    const int quad = lane >> 4;
    const int lr   = lane & 15;
    const int wr   = wave >> 1, wc = wave & 1;
    const int m0 = blockIdx.y * 128;
    const int n0 = blockIdx.x * 128;

    f32x4 acc[4][4];
#pragma unroll
    for (int i = 0; i < 4; i++)
#pragma unroll
        for (int j = 0; j < 4; j++) acc[i][j] = f32x4{0.f, 0.f, 0.f, 0.f};

    const int sl8 = lane >> 3;
    const int sc8 = ((lane & 7) ^ (sl8 & 7)) * 8;

    for (int k0 = 0; k0 < K; k0 += 64) {
        __syncthreads();  // prev-iter frag reads done
#pragma unroll
        for (int c = 0; c < 4; c++) {
            const int ii  = wave * 4 + c;
            const int row = ii * 8 + sl8;
            __builtin_amdgcn_global_load_lds(
                GLOBAL_CP(A + (size_t)(m0 + row) * K + k0 + sc8),
                LDS_CP(&As[ii * 512 + lane * 8]), 16, 0, 0);
            __builtin_amdgcn_global_load_lds(
                GLOBAL_CP(Bm + (size_t)(n0 + row) * K + k0 + sc8),
                LDS_CP(&Bs[ii * 512 + lane * 8]), 16, 0, 0);
        }
        __syncthreads();  // staging visible (vmcnt drain)

#pragma unroll
        for (int s = 0; s < 2; s++) {
            bf16x8 af[4], bfr[4];
#pragma unroll
            for (int i = 0; i < 4; i++) {
                const int R = wr * 64 + i * 16 + lr;
                af[i] = *(const bf16x8*)(&As[R * 64 + (((s * 4 + quad) ^ (R & 7)) << 3)]);
            }
#pragma unroll
            for (int j = 0; j < 4; j++) {
                const int R = wc * 64 + j * 16 + lr;
                bfr[j] = *(const bf16x8*)(&Bs[R * 64 + (((s * 4 + quad) ^ (R & 7)) << 3)]);
            }
#pragma unroll
            for (int i = 0; i < 4; i++)
#pragma unroll
                for (int j = 0; j < 4; j++)
                    acc[i][j] = __builtin_amdgcn_mfma_f32_16x16x32_bf16(
                        af[i], bfr[j], acc[i][j], 0, 0, 0);
        }
    }

    if (mode == 1 && blockIdx.x >= 16) {
        // ---- V path: LDS-bounce transpose, coalesced [bh][d][n] stores ----
        __syncthreads();               // all As/Bs frag readers done
        const int b    = m0 >> 11;
        const int t0_0 = m0 & 2047;
        const int h0   = (n0 - 2048) >> 6;
#pragma unroll
        for (int i = 0; i < 4; i++) {
            const int c8 = wr * 16 + i * 4 + quad;
#pragma unroll
            for (int j = 0; j < 4; j++) {
                const int dl = wc * 64 + j * 16 + lr;
                const int p8 = c8 ^ (lr << 1);
                union { uint2 u; bf16 hh[4]; } p;
#pragma unroll
                for (int r = 0; r < 4; r++) p.hh[r] = (bf16)acc[i][j][r];
                *(uint2*)((char*)smem + dl * 256 + p8 * 8) = p.u;
            }
        }
        __syncthreads();
#pragma unroll
        for (int k = 0; k < 8; k++) {
            const int cid = k * 256 + tid;
            const int row = cid >> 4;          // d_local 0..127
            const int c16 = cid & 15;          // logical 16B chunk (t0)
            const uint4 v = *(const uint4*)((const char*)smem
                                + row * 256 + ((c16 ^ (row & 15)) * 16));
            bf16* dst = vbT + ((size_t)(b * 16 + h0 + (row >> 6)) * 64
                               + (row & 63)) * 2048 + t0_0 + c16 * 8;
            *(uint4*)dst = v;
        }
        return;
    }

#pragma unroll
    for (int i = 0; i < 4; i++) {
        const int mbase = m0 + wr * 64 + i * 16 + quad * 4;
#pragma unroll
        for (int j = 0; j < 4; j++) {
            const int n = n0 + wc * 64 + j * 16 + lr;
            if (mode == 0) {
#pragma unroll
                for (int r = 0; r < 4; r++)
                    outf[(size_t)(mbase + r) * Ndim + n] = acc[i][j][r];
            } else {
                const int h = (n >> 6) & 15;
                const int d = n & 63;
                const int b  = mbase >> 11;
                const int t0 = mbase & 2047;
                bf16* dst = (n < 1024) ? qb : kbv;
                const float sc = (n < 1024) ? CEXP : 1.0f;
#pragma unroll
                for (int r = 0; r < 4; r++)
                    dst[(((size_t)(b * 16 + h)) * 2048 + t0 + r) * 64 + d] =
                        (bf16)(acc[i][j][r] * sc);
            }
        }
    }
}

// ---------------------------------------------------------------------------
// Dedicated proj GEMM: 64x128 tile -> grid (8,128) = 1024 blocks = 4.0
// blocks/CU (was 128x128 @ 512 blocks = 2.0/CU, 25% occupancy — the lowest-
// TLP kernel in the pipeline). LDS 24KB (A 8KB + B 16KB) -> 6 blocks LDS-cap;
// acc 2x4 (32 AGPR). A-staging is attn's verified 64x64 tile geometry;
// B-staging / frag reads / epilogue are gemm_bt's verbatim.
// out[m][n] = sum_k A[m][k] * Bm[n][k]  (fp32 out, row-major)
// ---------------------------------------------------------------------------
__global__ __launch_bounds__(256) void gemm_proj(
    const bf16* __restrict__ A, const bf16* __restrict__ Bm,
    float* __restrict__ outf)
{
    __shared__ bf16 As[64 * 64];     //  8192 B
    __shared__ bf16 Bs[128 * 64];    // 16384 B

    const int tid  = threadIdx.x;
    const int wave = tid >> 6;
    const int lane = tid & 63;
    const int quad = lane >> 4;
    const int lr   = lane & 15;
    const int wr   = wave >> 1, wc = wave & 1;   // wave tile: 32m x 64n
    const int m0 = blockIdx.y * 64;
    const int n0 = blockIdx.x * 128;

    f32x4 acc[2][4];
#pragma unroll
    for (int i = 0; i < 2; i++)
#pragma unroll
        for (int j = 0; j < 4; j++) acc[i][j] = f32x4{0.f, 0.f, 0.f, 0.f};

    const int sl8 = lane >> 3;
    const int sc8 = ((lane & 7) ^ (sl8 & 7)) * 8;

    for (int k0 = 0; k0 < DIM_; k0 += 64) {
        __syncthreads();  // prev-iter frag reads done
        // A: 64 rows (2 chunks/wave), B: 128 rows (4 chunks/wave)
#pragma unroll
        for (int c = 0; c < 2; c++) {
            const int ii  = wave * 2 + c;            // 0..7
            const int row = ii * 8 + sl8;            // 0..63
            __builtin_amdgcn_global_load_lds(
                GLOBAL_CP(A + (size_t)(m0 + row) * DIM_ + k0 + sc8),
                LDS_CP(&As[ii * 512 + lane * 8]), 16, 0, 0);
        }
#pragma unroll
        for (int c = 0; c < 4; c++) {
            const int ii  = wave * 4 + c;            // 0..15
            const int row = ii * 8 + sl8;            // 0..127
            __builtin_amdgcn_global_load_lds(
                GLOBAL_CP(Bm + (size_t)(n0 + row) * DIM_ + k0 + sc8),
                LDS_CP(&Bs[ii * 512 + lane * 8]), 16, 0, 0);
        }
        __syncthreads();  // staging visible (vmcnt drain)

#pragma unroll
        for (int s = 0; s < 2; s++) {
            bf16x8 af[2], bfr[4];
#pragma unroll
            for (int i = 0; i < 2; i++) {
                const int R = wr * 32 + i * 16 + lr;
                af[i] = *(const bf16x8*)(&As[R * 64 + (((s * 4 + quad) ^ (R & 7)) << 3)]);
            }
#pragma unroll
            for (int j = 0; j < 4; j++) {
                const int R = wc * 64 + j * 16 + lr;
                bfr[j] = *(const bf16x8*)(&Bs[R * 64 + (((s * 4 + quad) ^ (R & 7)) << 3)]);
            }
#pragma unroll
            for (int i = 0; i < 2; i++)
#pragma unroll
                for (int j = 0; j < 4; j++)
                    acc[i][j] = __builtin_amdgcn_mfma_f32_16x16x32_bf16(
                        af[i], bfr[j], acc[i][j], 0, 0, 0);
        }
    }

#pragma unroll
    for (int i = 0; i < 2; i++) {
        const int mbase = m0 + wr * 32 + i * 16 + quad * 4;
#pragma unroll
        for (int j = 0; j < 4; j++) {
            const int n = n0 + wc * 64 + j * 16 + lr;
#pragma unroll
            for (int r = 0; r < 4; r++)
                outf[(size_t)(mbase + r) * DIM_ + n] = acc[i][j][r];
        }
    }
}

// ---------------------------------------------------------------------------
// Flash attention v17 — R8-exact (best measured: attn 88.6µs). The 2-barrier
// structure's fitted optimum: hoisted kofs/vofs at the (256,3) budget,
// buf0/buf1 unrolled pairs, VALU row-sum + shfl epilogue, raw v_exp_f32,
// permlane32_swap exchange, 0-conflict paired-row K/V layout, dbuf DMA
// staging, setprio.
// ---------------------------------------------------------------------------
__global__ __launch_bounds__(256, 3) void attn_kernel(
    const bf16* __restrict__ qb, const bf16* __restrict__ kb,
    const bf16* __restrict__ vbT, bf16* __restrict__ ao)
{
    __shared__ bf16 Ks[2][32 * 128];   // 8KB per buffer, paired-key rows
    __shared__ bf16 Vs[2][32 * 128];   // 8KB per buffer, paired-d rows

    const int tid  = threadIdx.x;
    const int wave = tid >> 6;
    const int lane = tid & 63;
    const int l31  = lane & 31;
    const int hh   = lane >> 5;       // half-wave index

    // XCD swizzle: one head's 16 q-tiles on one XCD
    const int bid = blockIdx.x;
    const int qt  = (bid >> 3) & 15;
    const int bh  = ((bid >> 7) << 3) | (bid & 7);

    const bf16* Q  = qb  + (size_t)bh * N_ * DH_;
    const bf16* Kp = kb  + (size_t)bh * N_ * DH_;
    const bf16* Vp = vbT + (size_t)bh * DH_ * N_;   // [d][n]

    // Q B-frags: B[q=l31][d = ks*16 + hh*8 + j], loaded once from global
    bf16x8 qf[4];
#pragma unroll
    for (int ks = 0; ks < 4; ks++)
        qf[ks] = *(const bf16x8*)(Q + (size_t)(qt * 128 + wave * 32 + l31) * DH_
                                    + ks * 16 + hh * 8);

    // ---- hoisted LDS read byte-offsets (t-invariant) ----
    int kofs[8];   // [kbk*4 + ks]
#pragma unroll
    for (int kbk = 0; kbk < 2; kbk++)
#pragma unroll
        for (int ks = 0; ks < 4; ks++) {
            const int R  = kbk * 32 + l31;
            const int rr = R >> 1;
            const int ch = ks * 2 + hh;
            const int pc = (((R & 1) << 3) | ch) ^ (rr & 15);
            kofs[kbk * 4 + ks] = rr * 256 + pc * 16;
        }
    int vofs[8];   // [kbk*4 + dblk*2 + half]
#pragma unroll
    for (int kbk = 0; kbk < 2; kbk++)
#pragma unroll
        for (int dblk = 0; dblk < 2; dblk++)
#pragma unroll
            for (int half = 0; half < 2; half++) {
                const int Rv  = dblk * 32 + l31;
                const int rv  = Rv >> 1;
                const int chv = kbk * 4 + half * 2 + hh;
                const int pv_ = (((Rv & 1) << 3) | chv) ^ (rv & 15);
                vofs[kbk * 4 + dblk * 2 + half] = rv * 256 + pv_ * 16;
            }

    // ---- hoisted staging addresses ----
    const int sr = lane >> 4;
    const int sp = lane & 15;
    const bf16* ksrc[2];
    const bf16* vsrc[2];
    int sdst[2];
#pragma unroll
    for (int c2 = 0; c2 < 2; c2++) {
        const int ii  = wave * 2 + c2;
        const int rr2 = ii * 4 + sr;
        const int lc  = sp ^ (rr2 & 15);
        const int kk  = 2 * rr2 + (lc >> 3);
        const int d0  = (lc & 7) * 8;
        ksrc[c2] = Kp + (size_t)kk * DH_ + d0;   // t=0
        vsrc[c2] = Vp + (size_t)kk * N_ + d0;    // t=0
        sdst[c2] = ii * 1024 + lane * 16;        // bytes, buf0
    }

    const char* ksB = (const char*)Ks;
    const char* vsB = (const char*)Vs;
    char* ksBm = (char*)Ks;
    char* vsBm = (char*)Vs;

    f32x16 oacc[2];
#pragma unroll
    for (int r = 0; r < 16; r++) { oacc[0][r] = 0.f; oacc[1][r] = 0.f; }
    float lrow = 0.f;

#define STAGE()                                                               \
    {                                                                         \
        _Pragma("unroll")                                                     \
        for (int c2 = 0; c2 < 2; c2++) {                                      \
            __builtin_amdgcn_global_load_lds(GLOBAL_CP(ksrc[c2]),             \
                LDS_CP(ksBm + sdst[c2]), 16, 0, 0);                           \
            __builtin_amdgcn_global_load_lds(GLOBAL_CP(vsrc[c2]),             \
                LDS_CP(vsBm + sdst[c2]), 16, 0, 0);                           \
            ksrc[c2] += 64 * DH_;   /* +8192 B: next key-tile */              \
            vsrc[c2] += 64;         /* +128 B: next key-column */             \
            sdst[c2] ^= 8192;       /* alternate buffer */                    \
        }                                                                     \
    }

#define TILE(BUFB)                                                            \
    {                                                                         \
        float ssum = 0.f;                                                     \
        _Pragma("unroll")                                                     \
        for (int kbk = 0; kbk < 2; kbk++) {                                   \
            f32x16 e;                                                         \
            _Pragma("unroll")                                                 \
            for (int r = 0; r < 16; r++) e[r] = 0.f;                          \
            __builtin_amdgcn_s_setprio(1);                                    \
            _Pragma("unroll")                                                 \
            for (int ks = 0; ks < 4; ks++) {                                  \
                bf16x8 ak = *(const bf16x8*)(ksB + kofs[kbk * 4 + ks] + (BUFB)); \
                e = __builtin_amdgcn_mfma_f32_32x32x16_bf16(                  \
                        ak, qf[ks], e, 0, 0, 0);                              \
            }                                                                 \
            __builtin_amdgcn_s_setprio(0);                                    \
            bf16x8 bv[2][2];                                                  \
            _Pragma("unroll")                                                 \
            for (int dblk = 0; dblk < 2; dblk++)                              \
                _Pragma("unroll")                                             \
                for (int half = 0; half < 2; half++)                          \
                    bv[dblk][half] = *(const bf16x8*)(                        \
                        vsB + vofs[kbk * 4 + dblk * 2 + half] + (BUFB));      \
            _Pragma("unroll")                                                 \
            for (int r = 0; r < 16; r++) e[r] = __builtin_amdgcn_exp2f(e[r]); \
            _Pragma("unroll")                                                 \
            for (int r = 0; r < 16; r++) ssum += e[r];                        \
            uint g[8];                                                        \
            _Pragma("unroll")                                                 \
            for (int m = 0; m < 8; m++) {                                     \
                union { uint u; bf16 h2[2]; } pk;                             \
                pk.h2[0] = (bf16)e[2 * m];                                    \
                pk.h2[1] = (bf16)e[2 * m + 1];                                \
                g[m] = pk.u;                                                  \
            }                                                                 \
            const i32x2 s0 = __builtin_amdgcn_permlane32_swap((int)g[0], (int)g[2], false, false); \
            const i32x2 s1 = __builtin_amdgcn_permlane32_swap((int)g[1], (int)g[3], false, false); \
            const i32x2 s2 = __builtin_amdgcn_permlane32_swap((int)g[4], (int)g[6], false, false); \
            const i32x2 s3 = __builtin_amdgcn_permlane32_swap((int)g[5], (int)g[7], false, false); \
            union { uint u[4]; bf16x8 v; } p0u, p1u;                          \
            p0u.u[0] = (uint)s0[0]; p0u.u[1] = (uint)s1[0];                   \
            p0u.u[2] = (uint)s0[1]; p0u.u[3] = (uint)s1[1];                   \
            p1u.u[0] = (uint)s2[0]; p1u.u[1] = (uint)s3[0];                   \
            p1u.u[2] = (uint)s2[1]; p1u.u[3] = (uint)s3[1];                   \
            __builtin_amdgcn_s_setprio(1);                                    \
            _Pragma("unroll")                                                 \
            for (int dblk = 0; dblk < 2; dblk++) {                            \
                oacc[dblk] = __builtin_amdgcn_mfma_f32_32x32x16_bf16(         \
                    p0u.v, bv[dblk][0], oacc[dblk], 0, 0, 0);                 \
                oacc[dblk] = __builtin_amdgcn_mfma_f32_32x32x16_bf16(         \
                    p1u.v, bv[dblk][1], oacc[dblk], 0, 0, 0);                 \
            }                                                                 \
            __builtin_amdgcn_s_setprio(0);                                    \
        }                                                                     \
        ssum += __shfl_xor(ssum, 32);                                         \
        lrow += ssum;                                                         \
    }

    STAGE();             // t=0 -> buf0; srcs advance to t=1, dst -> buf1
    __syncthreads();     // tile 0 visible

    for (int tt = 0; tt < 16; tt++) {
        STAGE();         // t=2tt+1 -> buf1
        TILE(0);         // compute tile 2tt from buf0
        __syncthreads(); // buf1 staged; buf0 readers done
        if (tt < 15) STAGE();   // t=2tt+2 -> buf0
        TILE(8192);      // compute tile 2tt+1 from buf1
        __syncthreads(); // buf0 staged; buf1 readers done
    }
#undef STAGE
#undef TILE

    // epilogue: O row q=(r&3)+8*(r>>2)+4*hh, col d=dblk*32+l31.
    const int head = bh & 15;
    const int b    = bh >> 4;
    const float linv = 1.0f / lrow;     // valid at lane with l31 == q
#pragma unroll
    for (int r = 0; r < 16; r++) {
        const int qr  = (r & 3) + 8 * (r >> 2) + 4 * hh;
        const float inv = __shfl(linv, qr);     // lane qr holds q=qr
        const int qrow = qt * 128 + wave * 32 + qr;
#pragma unroll
        for (int dblk = 0; dblk < 2; dblk++)
            ao[((size_t)(b * 2048 + qrow)) * 1024 + head * 64 + dblk * 32 + l31] =
                (bf16)(oacc[dblk][r] * inv);
    }
}

// ---------------------------------------------------------------------------
extern "C" void kernel_launch(void* const* d_in, const int* in_sizes, int n_in,
                              void* d_out, int out_size, void* d_ws, size_t ws_size,
                              hipStream_t stream)
{
    const float* x     = (const float*)d_in[0];   // [8192 x 1024] fp32
    const float* wqkv  = (const float*)d_in[1];   // [3072 x 1024] fp32
    const float* wproj = (const float*)d_in[2];   // [1024 x 1024] fp32
    float* out = (float*)d_out;                   // [8192 x 1024] fp32

    const size_t nx  = (size_t)M_ * DIM_;
    const size_t nwq = (size_t)3 * DIM_ * DIM_;
    const size_t nwp = (size_t)DIM_ * DIM_;
    const size_t seg = (size_t)B_ * H_ * N_ * DH_;

    bf16* xb     = (bf16*)d_ws;        // dead after QKV gemm; ao overlays it
    bf16* wqkvb  = xb + nx;            // contiguous with xb (cvt_all dest)
    bf16* wprojb = wqkvb + nwq;
    bf16* qb     = wprojb + nwp;
    bf16* kb     = qb + seg;
    bf16* vbT    = kb + seg;           // [bh][d][n]
    bf16* ao     = xb;

    const int nx4  = (int)(nx / 4), nwq4 = (int)(nwq / 4), nwp4 = (int)(nwp / 4);
    cvt_all<<<(nx4 + nwq4 + nwp4) / 512, 256, 0, stream>>>(
        x, wqkv, wproj, xb, nx4, nwq4, nwp4);

    gemm_bt<<<dim3(24, 64), 256, 0, stream>>>(xb, wqkvb, 3 * DIM_, DIM_, 1,
                                              nullptr, qb, kb, vbT);
    attn_kernel<<<dim3(1024), 256, 0, stream>>>(qb, kb, vbT, ao);
    gemm_proj<<<dim3(8, 128), 256, 0, stream>>>(ao, wprojb, out);
}